// Round 1
// baseline (2113.263 us; speedup 1.0000x reference)
//
#include <hip/hip_runtime.h>

#define N_NODES 50000
#define N_EDGES 800000
#define BATCH   32

// ---------------------------------------------------------------------------
// Pass 1: degree count (indegree via dst; +1 self-loop added at use time)
// deg is float so pass 2 can rsqrt it directly; counts are exact in fp32.
// ---------------------------------------------------------------------------
__global__ void deg_kernel(const int* __restrict__ ei, float* __restrict__ deg) {
    const int b = blockIdx.y;
    const int* __restrict__ dst = ei + (size_t)b * (2 * (size_t)N_EDGES) + N_EDGES;
    float* __restrict__ degb = deg + (size_t)b * N_NODES;
    for (int e = blockIdx.x * blockDim.x + threadIdx.x; e < N_EDGES;
         e += gridDim.x * blockDim.x) {
        atomicAdd(&degb[dst[e]], 1.0f);
    }
}

// ---------------------------------------------------------------------------
// Pass 2: s[b][c] = sum over (edges + self-loops) of xg[b, src, c] * w
//   edge:      w = rsqrt(deg[src]+1) * rsqrt(deg[dst]+1)
//   self-loop: w = 1 / (deg[n]+1)
// Per-thread 10-float accumulator -> wave shuffle reduce -> LDS -> atomics.
// ---------------------------------------------------------------------------
__global__ void edge_sum_kernel(const int* __restrict__ ei,
                                const float* __restrict__ xg,
                                const float* __restrict__ deg,
                                float* __restrict__ s) {
    const int b = blockIdx.y;
    const int* __restrict__ src = ei + (size_t)b * (2 * (size_t)N_EDGES);
    const int* __restrict__ dst = src + N_EDGES;
    const float* __restrict__ degb = deg + (size_t)b * N_NODES;
    const float2* __restrict__ xgb =
        reinterpret_cast<const float2*>(xg) + (size_t)b * (N_NODES * 10 / 2);

    float acc[10];
#pragma unroll
    for (int c = 0; c < 10; ++c) acc[c] = 0.0f;

    const int total = N_EDGES + N_NODES;
    for (int i = blockIdx.x * blockDim.x + threadIdx.x; i < total;
         i += gridDim.x * blockDim.x) {
        int node;
        float w;
        if (i < N_EDGES) {
            const int u = src[i];
            const int v = dst[i];
            node = u;
            w = rsqrtf(degb[u] + 1.0f) * rsqrtf(degb[v] + 1.0f);
        } else {
            node = i - N_EDGES;
            w = 1.0f / (degb[node] + 1.0f);
        }
        const float2* __restrict__ row = xgb + (size_t)node * 5;
        const float2 r0 = row[0], r1 = row[1], r2 = row[2], r3 = row[3], r4 = row[4];
        acc[0] += r0.x * w; acc[1] += r0.y * w;
        acc[2] += r1.x * w; acc[3] += r1.y * w;
        acc[4] += r2.x * w; acc[5] += r2.y * w;
        acc[6] += r3.x * w; acc[7] += r3.y * w;
        acc[8] += r4.x * w; acc[9] += r4.y * w;
    }

    // wave (64-lane) shuffle reduction
#pragma unroll
    for (int c = 0; c < 10; ++c) {
#pragma unroll
        for (int off = 32; off > 0; off >>= 1)
            acc[c] += __shfl_down(acc[c], off);
    }

    __shared__ float sm[4][10];  // 256 threads = 4 waves
    const int wave = threadIdx.x >> 6;
    const int lane = threadIdx.x & 63;
    if (lane == 0) {
#pragma unroll
        for (int c = 0; c < 10; ++c) sm[wave][c] = acc[c];
    }
    __syncthreads();
    if (threadIdx.x < 10) {
        const float v = sm[0][threadIdx.x] + sm[1][threadIdx.x] +
                        sm[2][threadIdx.x] + sm[3][threadIdx.x];
        atomicAdd(&s[b * 16 + threadIdx.x], v);
    }
}

// ---------------------------------------------------------------------------
// Pass 3: tiny MLP + log_softmax(axis=0). One block; speed irrelevant (~µs).
// ---------------------------------------------------------------------------
__global__ void mlp_kernel(const float* __restrict__ s,
                           const float* __restrict__ x,
                           const float* __restrict__ W_gcn,
                           const float* __restrict__ b_gcn,
                           const float* __restrict__ W1, const float* __restrict__ b1,
                           const float* __restrict__ W2, const float* __restrict__ b2,
                           const float* __restrict__ Wo, const float* __restrict__ bo,
                           float* __restrict__ out) {
    __shared__ float h0[32][20];
    __shared__ float h1[32][80];
    __shared__ float h2[32][160];
    __shared__ float o[32][4];
    const int tid = threadIdx.x;

    // h0 = [pooled | x];  pooled = (s @ W_gcn)/N + b_gcn
    for (int idx = tid; idx < 32 * 20; idx += blockDim.x) {
        const int b = idx / 20, j = idx % 20;
        float v;
        if (j < 10) {
            v = 0.0f;
#pragma unroll
            for (int k = 0; k < 10; ++k) v += s[b * 16 + k] * W_gcn[k * 10 + j];
            v = v * (1.0f / (float)N_NODES) + b_gcn[j];
        } else {
            v = x[b * 10 + (j - 10)];
        }
        h0[b][j] = v;
    }
    __syncthreads();

    for (int idx = tid; idx < 32 * 80; idx += blockDim.x) {
        const int b = idx / 80, j = idx % 80;
        float v = b1[j];
#pragma unroll
        for (int k = 0; k < 20; ++k) v += h0[b][k] * W1[k * 80 + j];
        h1[b][j] = (v > 0.0f) ? v : 0.01f * v;
    }
    __syncthreads();

    for (int idx = tid; idx < 32 * 160; idx += blockDim.x) {
        const int b = idx / 160, j = idx % 160;
        float v = b2[j];
        for (int k = 0; k < 80; ++k) v += h1[b][k] * W2[k * 160 + j];
        h2[b][j] = (v > 0.0f) ? v : 0.01f * v;
    }
    __syncthreads();

    for (int idx = tid; idx < 32 * 4; idx += blockDim.x) {
        const int b = idx / 4, j = idx % 4;
        float v = bo[j];
        for (int k = 0; k < 160; ++k) v += h2[b][k] * Wo[k * 4 + j];
        o[b][j] = v;
    }
    __syncthreads();

    // log_softmax over axis 0 (the 32 batch rows), per column
    if (tid < 4) {
        float m = -1e30f;
        for (int b = 0; b < 32; ++b) m = fmaxf(m, o[b][tid]);
        float lse = 0.0f;
        for (int b = 0; b < 32; ++b) lse += expf(o[b][tid] - m);
        lse = logf(lse);
        for (int b = 0; b < 32; ++b) out[b * 4 + tid] = o[b][tid] - m - lse;
    }
}

extern "C" void kernel_launch(void* const* d_in, const int* in_sizes, int n_in,
                              void* d_out, int out_size, void* d_ws, size_t ws_size,
                              hipStream_t stream) {
    const float* x      = (const float*)d_in[0];   // [32,10]
    const float* gcn_x  = (const float*)d_in[1];   // [32,50000,10]
    const int*   ei     = (const int*)d_in[2];     // [32,2,800000] int32
    const float* W_gcn  = (const float*)d_in[3];   // [10,10]
    const float* b_gcn  = (const float*)d_in[4];   // [10]
    const float* W1     = (const float*)d_in[5];   // [20,80]
    const float* b1     = (const float*)d_in[6];   // [80]
    const float* W2     = (const float*)d_in[7];   // [80,160]
    const float* b2     = (const float*)d_in[8];   // [160]
    const float* Wo     = (const float*)d_in[9];   // [160,4]
    const float* bo     = (const float*)d_in[10];  // [4]
    float* out = (float*)d_out;                    // [32,4]

    // workspace layout: deg [32*50000] floats, then s [32*16] floats
    float* deg = (float*)d_ws;
    float* s   = deg + (size_t)BATCH * N_NODES;
    const size_t zero_bytes = ((size_t)BATCH * N_NODES + BATCH * 16) * sizeof(float);
    hipMemsetAsync(d_ws, 0, zero_bytes, stream);

    {
        dim3 grid(512, BATCH);
        deg_kernel<<<grid, 256, 0, stream>>>(ei, deg);
    }
    {
        dim3 grid(128, BATCH);
        edge_sum_kernel<<<grid, 256, 0, stream>>>(ei, gcn_x, deg, s);
    }
    mlp_kernel<<<1, 256, 0, stream>>>(s, x, W_gcn, b_gcn, W1, b1, W2, b2, Wo, bo, out);
}

// Round 2
// 520.439 us; speedup vs baseline: 4.0605x; 4.0605x over previous
//
#include <hip/hip_runtime.h>

#define N_NODES 50000
#define N_EDGES 800000
#define BATCH   32
#define NWORD8  12500   // N_NODES/4 u32 words, u8-packed degree counts
#define NHALF   25000   // nodes per half-range for c-scatter
#define NWORD16 12500   // NHALF/2 u32 words, u16-packed c
#define CHUNKS  8
#define EPC4    25000   // int4 loads per chunk (= 100000 edges)
#define QSCALE  1024.0f

// ---------------------------------------------------------------------------
// K1: per-(batch,chunk) degree histogram in LDS (u8 packed x4 per u32 word).
// Per-slice per-node count ~ Poisson(2): u8 overflow impossible in practice.
// Partials written contiguously — NO global atomics.
// ---------------------------------------------------------------------------
__global__ __launch_bounds__(1024) void hist_kernel(const int* __restrict__ ei,
                                                    unsigned* __restrict__ partials) {
    const int chunk = blockIdx.x, b = blockIdx.y;
    __shared__ unsigned cnt[NWORD8];  // 50 KB
    for (int i = threadIdx.x; i < NWORD8; i += 1024) cnt[i] = 0;
    __syncthreads();
    const int4* __restrict__ dst4 =
        (const int4*)(ei + (size_t)b * (2 * N_EDGES) + N_EDGES) + (size_t)chunk * EPC4;
    for (int i = threadIdx.x; i < EPC4; i += 1024) {
        const int4 v = dst4[i];
        atomicAdd(&cnt[((unsigned)v.x) >> 2], 1u << ((v.x & 3) * 8));
        atomicAdd(&cnt[((unsigned)v.y) >> 2], 1u << ((v.y & 3) * 8));
        atomicAdd(&cnt[((unsigned)v.z) >> 2], 1u << ((v.z & 3) * 8));
        atomicAdd(&cnt[((unsigned)v.w) >> 2], 1u << ((v.w & 3) * 8));
    }
    __syncthreads();
    unsigned* __restrict__ out = partials + (size_t)(b * CHUNKS + chunk) * NWORD8;
    for (int i = threadIdx.x; i < NWORD8; i += 1024) out[i] = cnt[i];
}

// ---------------------------------------------------------------------------
// K2: reduce degree partials -> dinv[b][n] = rsqrt(count+1)  (f32)
//     and qdinv = round(dinv * 1024) as packed u16 (for the c-scatter gather).
// ---------------------------------------------------------------------------
__global__ void dinv_kernel(const unsigned* __restrict__ partials,
                            float* __restrict__ dinv,
                            unsigned* __restrict__ qdinv) {
    const int idx = blockIdx.x * 256 + threadIdx.x;
    if (idx >= BATCH * NWORD8) return;
    const int b = idx / NWORD8, i = idx - b * NWORD8;
    const unsigned* __restrict__ p = partials + (size_t)(b * CHUNKS) * NWORD8 + i;
    unsigned d0 = 0, d1 = 0, d2 = 0, d3 = 0;
#pragma unroll
    for (int c = 0; c < CHUNKS; ++c) {
        const unsigned v = p[(size_t)c * NWORD8];
        d0 += v & 0xFF; d1 += (v >> 8) & 0xFF; d2 += (v >> 16) & 0xFF; d3 += v >> 24;
    }
    const float i0 = rsqrtf((float)(d0 + 1));
    const float i1 = rsqrtf((float)(d1 + 1));
    const float i2 = rsqrtf((float)(d2 + 1));
    const float i3 = rsqrtf((float)(d3 + 1));
    float4* dv4 = (float4*)(dinv + (size_t)b * N_NODES) + i;
    *dv4 = make_float4(i0, i1, i2, i3);
    const unsigned q0 = __float2uint_rn(i0 * QSCALE);
    const unsigned q1 = __float2uint_rn(i1 * QSCALE);
    const unsigned q2 = __float2uint_rn(i2 * QSCALE);
    const unsigned q3 = __float2uint_rn(i3 * QSCALE);
    uint2* qq = (uint2*)(qdinv + (size_t)b * (N_NODES / 2)) + i;
    *qq = make_uint2(q0 | (q1 << 16), q2 | (q3 << 16));
}

// ---------------------------------------------------------------------------
// K3: c[n] = sum over out-edges of n of dinv[dst], as u16 fixed-point LDS
// histogram over a half node-range (50 KB). Swizzle: batch pinned to XCD
// (id%8), half pairs adjacent in schedule -> edge slice re-read hits L2;
// qdinv gather region (100 KB x 4 batches) stays L2-resident per XCD.
// ---------------------------------------------------------------------------
__global__ __launch_bounds__(1024) void cscat_kernel(const int* __restrict__ ei,
                                                     const unsigned short* __restrict__ qdinv,
                                                     unsigned* __restrict__ cpart) {
    const int id = blockIdx.x;  // 512 = 8 xcd * 2 half * 4 bgroup * 8 chunk
    const int r = id & 7, t = id >> 3;
    const int half = t & 1, q = t >> 1;
    const int b = r + 8 * (q & 3), chunk = q >> 2;
    __shared__ unsigned cs[NWORD16];  // 50 KB
    for (int i = threadIdx.x; i < NWORD16; i += 1024) cs[i] = 0;
    __syncthreads();
    const int* eb = ei + (size_t)b * (2 * N_EDGES);
    const int4* __restrict__ src4 = (const int4*)eb + (size_t)chunk * EPC4;
    const int4* __restrict__ dst4 = (const int4*)(eb + N_EDGES) + (size_t)chunk * EPC4;
    const unsigned short* __restrict__ qd = qdinv + (size_t)b * N_NODES;
    const int lo = half * NHALF;
    for (int i = threadIdx.x; i < EPC4; i += 1024) {
        const int4 s4 = src4[i];
        const int4 d4 = dst4[i];
        unsigned loc;
        loc = (unsigned)(s4.x - lo);
        if (loc < NHALF) atomicAdd(&cs[loc >> 1], (unsigned)qd[d4.x] << ((loc & 1) * 16));
        loc = (unsigned)(s4.y - lo);
        if (loc < NHALF) atomicAdd(&cs[loc >> 1], (unsigned)qd[d4.y] << ((loc & 1) * 16));
        loc = (unsigned)(s4.z - lo);
        if (loc < NHALF) atomicAdd(&cs[loc >> 1], (unsigned)qd[d4.z] << ((loc & 1) * 16));
        loc = (unsigned)(s4.w - lo);
        if (loc < NHALF) atomicAdd(&cs[loc >> 1], (unsigned)qd[d4.w] << ((loc & 1) * 16));
    }
    __syncthreads();
    unsigned* __restrict__ out = cpart + (size_t)((b * CHUNKS + chunk) * 2 + half) * NWORD16;
    for (int i = threadIdx.x; i < NWORD16; i += 1024) out[i] = cs[i];
}

// ---------------------------------------------------------------------------
// K4: w[b][n] = dinv * (c + dinv)   (the +dinv folds the self-loop dinv^2)
// ---------------------------------------------------------------------------
__global__ void w_kernel(const unsigned* __restrict__ cpart,
                         const float* __restrict__ dinv,
                         float* __restrict__ w) {
    const int idx = blockIdx.x * 256 + threadIdx.x;
    if (idx >= BATCH * 2 * NWORD16) return;
    const int b = idx / (2 * NWORD16);
    const int j = idx - b * (2 * NWORD16);
    const int half = j / NWORD16, i = j - half * NWORD16;
    const unsigned* __restrict__ p = cpart + (size_t)((b * CHUNKS) * 2 + half) * NWORD16 + i;
    unsigned c0 = 0, c1 = 0;
#pragma unroll
    for (int c = 0; c < CHUNKS; ++c) {
        const unsigned v = p[(size_t)c * 2 * NWORD16];
        c0 += v & 0xFFFF; c1 += v >> 16;
    }
    const int node = half * NHALF + 2 * i;
    const float2 d = *((const float2*)(dinv + (size_t)b * N_NODES + node));
    const float f0 = (float)c0 * (1.0f / QSCALE);
    const float f1 = (float)c1 * (1.0f / QSCALE);
    *((float2*)(w + (size_t)b * N_NODES + node)) = make_float2(d.x * (f0 + d.x), d.y * (f1 + d.y));
}

// ---------------------------------------------------------------------------
// K5: s[b][:] = sum_n xg[b,n,:] * w[b,n]  — fully coalesced weighted col-sum.
// 320 threads (5 waves): p = tid%5 is a CONSTANT column-pair per thread
// (320 % 5 == 0, base % 5 == 0) so a wave reads 512 contiguous bytes.
// ---------------------------------------------------------------------------
__global__ __launch_bounds__(320) void pool_kernel(const float* __restrict__ xg,
                                                   const float* __restrict__ w,
                                                   float* __restrict__ s) {
    const int chunk = blockIdx.x, b = blockIdx.y;  // grid (16, 32)
    const float2* __restrict__ xg2 = (const float2*)xg;
    const int base = b * 250000 + chunk * 15625;  // float2 index; base % 5 == 0
    const int p = threadIdx.x % 5;
    float ax = 0.0f, ay = 0.0f;
    for (int j = threadIdx.x; j < 15625; j += 320) {
        const int f = base + j;
        const float wv = w[f / 5];  // == b*50000 + node
        const float2 v = xg2[f];
        ax += v.x * wv; ay += v.y * wv;
    }
    __shared__ float sacc[10];
    if (threadIdx.x < 10) sacc[threadIdx.x] = 0.0f;
    __syncthreads();
    atomicAdd(&sacc[2 * p], ax);
    atomicAdd(&sacc[2 * p + 1], ay);
    __syncthreads();
    if (threadIdx.x < 10) atomicAdd(&s[b * 16 + threadIdx.x], sacc[threadIdx.x]);
}

// ---------------------------------------------------------------------------
// K6: tiny MLP + log_softmax(axis=0). One block; ~µs.
// ---------------------------------------------------------------------------
__global__ void mlp_kernel(const float* __restrict__ s,
                           const float* __restrict__ x,
                           const float* __restrict__ W_gcn,
                           const float* __restrict__ b_gcn,
                           const float* __restrict__ W1, const float* __restrict__ b1,
                           const float* __restrict__ W2, const float* __restrict__ b2,
                           const float* __restrict__ Wo, const float* __restrict__ bo,
                           float* __restrict__ out) {
    __shared__ float h0[32][20];
    __shared__ float h1[32][80];
    __shared__ float h2[32][160];
    __shared__ float o[32][4];
    const int tid = threadIdx.x;

    for (int idx = tid; idx < 32 * 20; idx += blockDim.x) {
        const int b = idx / 20, j = idx % 20;
        float v;
        if (j < 10) {
            v = 0.0f;
#pragma unroll
            for (int k = 0; k < 10; ++k) v += s[b * 16 + k] * W_gcn[k * 10 + j];
            v = v * (1.0f / (float)N_NODES) + b_gcn[j];
        } else {
            v = x[b * 10 + (j - 10)];
        }
        h0[b][j] = v;
    }
    __syncthreads();

    for (int idx = tid; idx < 32 * 80; idx += blockDim.x) {
        const int b = idx / 80, j = idx % 80;
        float v = b1[j];
#pragma unroll
        for (int k = 0; k < 20; ++k) v += h0[b][k] * W1[k * 80 + j];
        h1[b][j] = (v > 0.0f) ? v : 0.01f * v;
    }
    __syncthreads();

    for (int idx = tid; idx < 32 * 160; idx += blockDim.x) {
        const int b = idx / 160, j = idx % 160;
        float v = b2[j];
        for (int k = 0; k < 80; ++k) v += h1[b][k] * W2[k * 160 + j];
        h2[b][j] = (v > 0.0f) ? v : 0.01f * v;
    }
    __syncthreads();

    for (int idx = tid; idx < 32 * 4; idx += blockDim.x) {
        const int b = idx / 4, j = idx % 4;
        float v = bo[j];
        for (int k = 0; k < 160; ++k) v += h2[b][k] * Wo[k * 4 + j];
        o[b][j] = v;
    }
    __syncthreads();

    if (tid < 4) {
        float m = -1e30f;
        for (int b = 0; b < 32; ++b) m = fmaxf(m, o[b][tid]);
        float lse = 0.0f;
        for (int b = 0; b < 32; ++b) lse += expf(o[b][tid] - m);
        lse = logf(lse);
        for (int b = 0; b < 32; ++b) out[b * 4 + tid] = o[b][tid] - m - lse;
    }
}

extern "C" void kernel_launch(void* const* d_in, const int* in_sizes, int n_in,
                              void* d_out, int out_size, void* d_ws, size_t ws_size,
                              hipStream_t stream) {
    const float* x      = (const float*)d_in[0];
    const float* gcn_x  = (const float*)d_in[1];
    const int*   ei     = (const int*)d_in[2];
    const float* W_gcn  = (const float*)d_in[3];
    const float* b_gcn  = (const float*)d_in[4];
    const float* W1     = (const float*)d_in[5];
    const float* b1     = (const float*)d_in[6];
    const float* W2     = (const float*)d_in[7];
    const float* b2     = (const float*)d_in[8];
    const float* Wo     = (const float*)d_in[9];
    const float* bo     = (const float*)d_in[10];
    float* out = (float*)d_out;

    // workspace layout (offsets in bytes):
    //   s        [32*16 f32]            @ 0          (2 KB, zeroed)
    //   partials [512*12500 u32]        @ 2048       (25.6 MB; K1 uses first half, K3 reuses all)
    //   dinv     [32*50000 f32]         @ 25,602,048 (6.4 MB)
    //   qdinv    [32*25000 u32 packed]  @ 32,002,048 (3.2 MB)
    //   w        [32*50000 f32]         @ 35,202,048 (6.4 MB)   total ~41.6 MB
    float*    s        = (float*)d_ws;
    unsigned* partials = (unsigned*)((char*)d_ws + 2048);
    float*    dinv     = (float*)((char*)d_ws + 2048 + (size_t)512 * NWORD16 * 4);
    unsigned* qdinv    = (unsigned*)((char*)dinv + (size_t)BATCH * N_NODES * 4);
    float*    w        = (float*)((char*)qdinv + (size_t)BATCH * (N_NODES / 2) * 4);

    hipMemsetAsync(s, 0, BATCH * 16 * sizeof(float), stream);

    {   // K1: degree histograms
        dim3 grid(CHUNKS, BATCH);
        hist_kernel<<<grid, 1024, 0, stream>>>(ei, partials);
    }
    {   // K2: reduce -> dinv, qdinv
        const int n = BATCH * NWORD8;
        dinv_kernel<<<(n + 255) / 256, 256, 0, stream>>>(partials, dinv, qdinv);
    }
    {   // K3: c-scatter histograms (512 swizzled blocks)
        cscat_kernel<<<512, 1024, 0, stream>>>(ei, (const unsigned short*)qdinv, partials);
    }
    {   // K4: w = dinv*(c+dinv)
        const int n = BATCH * 2 * NWORD16;
        w_kernel<<<(n + 255) / 256, 256, 0, stream>>>(partials, dinv, w);
    }
    {   // K5: pooled weighted column-sum
        dim3 grid(16, BATCH);
        pool_kernel<<<grid, 320, 0, stream>>>(gcn_x, w, s);
    }
    mlp_kernel<<<1, 256, 0, stream>>>(s, x, W_gcn, b_gcn, W1, b1, W2, b2, Wo, bo, out);
}

// Round 3
// 516.219 us; speedup vs baseline: 4.0937x; 1.0082x over previous
//
#include <hip/hip_runtime.h>

#define N_NODES 50000
#define N_EDGES 800000
#define BATCH   32
#define NWORD8  12500   // N_NODES/4 u32 words, u8-packed degree counts
#define NWORDC  25000   // N_NODES/2 u32 words, u16-packed c (full range, 100 KB)
#define CHUNKS  8
#define EPC4    25000   // int4 loads per chunk (= 100000 edges)
#define QSCALE  1024.0f

// ---------------------------------------------------------------------------
// K1: per-(batch,chunk) degree histogram in LDS (u8 packed x4 per u32 word).
// Per-slice per-node count ~ Poisson(2): u8 overflow impossible in practice.
// Partials written contiguously — NO global atomics.
// ---------------------------------------------------------------------------
__global__ __launch_bounds__(1024) void hist_kernel(const int* __restrict__ ei,
                                                    unsigned* __restrict__ partials) {
    const int chunk = blockIdx.x, b = blockIdx.y;
    __shared__ unsigned cnt[NWORD8];  // 50 KB
    for (int i = threadIdx.x; i < NWORD8; i += 1024) cnt[i] = 0;
    __syncthreads();
    const int4* __restrict__ dst4 =
        (const int4*)(ei + (size_t)b * (2 * N_EDGES) + N_EDGES) + (size_t)chunk * EPC4;
    for (int i = threadIdx.x; i < EPC4; i += 1024) {
        const int4 v = dst4[i];
        atomicAdd(&cnt[((unsigned)v.x) >> 2], 1u << ((v.x & 3) * 8));
        atomicAdd(&cnt[((unsigned)v.y) >> 2], 1u << ((v.y & 3) * 8));
        atomicAdd(&cnt[((unsigned)v.z) >> 2], 1u << ((v.z & 3) * 8));
        atomicAdd(&cnt[((unsigned)v.w) >> 2], 1u << ((v.w & 3) * 8));
    }
    __syncthreads();
    unsigned* __restrict__ out = partials + (size_t)(b * CHUNKS + chunk) * NWORD8;
    for (int i = threadIdx.x; i < NWORD8; i += 1024) out[i] = cnt[i];
}

// ---------------------------------------------------------------------------
// K2: reduce degree partials -> dinv[b][n] = rsqrt(count+1)  (f32)
//     and qdinv = round(dinv * 1024) as packed u16 (for the c-scatter gather).
// ---------------------------------------------------------------------------
__global__ void dinv_kernel(const unsigned* __restrict__ partials,
                            float* __restrict__ dinv,
                            unsigned* __restrict__ qdinv) {
    const int idx = blockIdx.x * 256 + threadIdx.x;
    if (idx >= BATCH * NWORD8) return;
    const int b = idx / NWORD8, i = idx - b * NWORD8;
    const unsigned* __restrict__ p = partials + (size_t)(b * CHUNKS) * NWORD8 + i;
    unsigned d0 = 0, d1 = 0, d2 = 0, d3 = 0;
#pragma unroll
    for (int c = 0; c < CHUNKS; ++c) {
        const unsigned v = p[(size_t)c * NWORD8];
        d0 += v & 0xFF; d1 += (v >> 8) & 0xFF; d2 += (v >> 16) & 0xFF; d3 += v >> 24;
    }
    const float i0 = rsqrtf((float)(d0 + 1));
    const float i1 = rsqrtf((float)(d1 + 1));
    const float i2 = rsqrtf((float)(d2 + 1));
    const float i3 = rsqrtf((float)(d3 + 1));
    float4* dv4 = (float4*)(dinv + (size_t)b * N_NODES) + i;
    *dv4 = make_float4(i0, i1, i2, i3);
    const unsigned q0 = __float2uint_rn(i0 * QSCALE);
    const unsigned q1 = __float2uint_rn(i1 * QSCALE);
    const unsigned q2 = __float2uint_rn(i2 * QSCALE);
    const unsigned q3 = __float2uint_rn(i3 * QSCALE);
    uint2* qq = (uint2*)(qdinv + (size_t)b * (N_NODES / 2)) + i;
    *qq = make_uint2(q0 | (q1 << 16), q2 | (q3 << 16));
}

// ---------------------------------------------------------------------------
// K3: c[n] = sum over out-edges of n of dinv[dst], u16 fixed-point histogram
// over the FULL node range (100 KB dynamic LDS). All 64 lanes active on every
// gather/atomic; each edge read exactly once. 256 blocks = 1/CU (16 waves).
// Swizzle: id%8 = XCD, 4 batches per XCD -> qdinv gather set 400 KB/XCD in L2.
// u16 overflow needs >=64 same-src hits in a 100k-edge chunk: P ~ 1e-44.
// ---------------------------------------------------------------------------
__global__ __launch_bounds__(1024) void cscat_kernel(const int* __restrict__ ei,
                                                     const unsigned short* __restrict__ qdinv,
                                                     unsigned* __restrict__ cpart) {
    extern __shared__ unsigned cs[];  // NWORDC = 100 KB
    const int id = blockIdx.x;  // 256 = 8 xcd * 4 bgroup * 8 chunk
    const int b = (id & 7) + 8 * ((id >> 3) & 3);
    const int chunk = id >> 5;
    for (int i = threadIdx.x; i < NWORDC; i += 1024) cs[i] = 0;
    __syncthreads();
    const int* eb = ei + (size_t)b * (2 * N_EDGES);
    const int4* __restrict__ src4 = (const int4*)eb + (size_t)chunk * EPC4;
    const int4* __restrict__ dst4 = (const int4*)(eb + N_EDGES) + (size_t)chunk * EPC4;
    const unsigned short* __restrict__ qd = qdinv + (size_t)b * N_NODES;
    for (int i = threadIdx.x; i < EPC4; i += 1024) {
        const int4 s4 = src4[i];
        const int4 d4 = dst4[i];
        const unsigned q0 = qd[d4.x];
        const unsigned q1 = qd[d4.y];
        const unsigned q2 = qd[d4.z];
        const unsigned q3 = qd[d4.w];
        atomicAdd(&cs[((unsigned)s4.x) >> 1], q0 << ((s4.x & 1) << 4));
        atomicAdd(&cs[((unsigned)s4.y) >> 1], q1 << ((s4.y & 1) << 4));
        atomicAdd(&cs[((unsigned)s4.z) >> 1], q2 << ((s4.z & 1) << 4));
        atomicAdd(&cs[((unsigned)s4.w) >> 1], q3 << ((s4.w & 1) << 4));
    }
    __syncthreads();
    unsigned* __restrict__ out = cpart + (size_t)(b * CHUNKS + chunk) * NWORDC;
    for (int i = threadIdx.x; i < NWORDC; i += 1024) out[i] = cs[i];
}

// ---------------------------------------------------------------------------
// K4: w[b][n] = dinv * (c + dinv)   (the +dinv folds the self-loop dinv^2)
// ---------------------------------------------------------------------------
__global__ void w_kernel(const unsigned* __restrict__ cpart,
                         const float* __restrict__ dinv,
                         float* __restrict__ w) {
    const int idx = blockIdx.x * 256 + threadIdx.x;
    if (idx >= BATCH * NWORDC) return;
    const int b = idx / NWORDC, i = idx - b * NWORDC;
    const unsigned* __restrict__ p = cpart + (size_t)(b * CHUNKS) * NWORDC + i;
    unsigned c0 = 0, c1 = 0;
#pragma unroll
    for (int c = 0; c < CHUNKS; ++c) {
        const unsigned v = p[(size_t)c * NWORDC];
        c0 += v & 0xFFFF; c1 += v >> 16;
    }
    const int node = 2 * i;
    const float2 d = *((const float2*)(dinv + (size_t)b * N_NODES + node));
    const float f0 = (float)c0 * (1.0f / QSCALE);
    const float f1 = (float)c1 * (1.0f / QSCALE);
    *((float2*)(w + (size_t)b * N_NODES + node)) = make_float2(d.x * (f0 + d.x), d.y * (f1 + d.y));
}

// ---------------------------------------------------------------------------
// K5: s[b][:] = sum_n xg[b,n,:] * w[b,n] — float4 coalesced weighted col-sum.
// 320 threads: 4*320 % 10 == 0 so each lane's 4 channels are loop-invariant.
// ---------------------------------------------------------------------------
__global__ __launch_bounds__(320) void pool_kernel(const float* __restrict__ xg,
                                                   const float* __restrict__ w,
                                                   float* __restrict__ s) {
    const int chunk = blockIdx.x, b = blockIdx.y;  // grid (8, 32)
    const float4* __restrict__ xg4 = (const float4*)xg;
    const int base4 = b * 125000 + chunk * 15625;  // float4 index; 4*base4 % 10 == 0
    const int r = (4 * threadIdx.x) % 10;          // element phase, fixed per lane
    float a0 = 0.0f, a1 = 0.0f, a2 = 0.0f, a3 = 0.0f;
    for (int j = threadIdx.x; j < 15625; j += 320) {
        const int f4 = base4 + j;
        const int e0 = f4 * 4;             // global element idx; w idx = e0/10
        const float4 v = xg4[f4];
        const float w0 = w[e0 / 10];
        const float w1 = (r == 8) ? w[e0 / 10 + 1] : w0;  // r==8: z,w cross node boundary
        a0 += v.x * w0;
        a1 += v.y * w0;
        a2 += v.z * w1;
        a3 += v.w * w1;
    }
    __shared__ float sacc[10];
    if (threadIdx.x < 10) sacc[threadIdx.x] = 0.0f;
    __syncthreads();
    atomicAdd(&sacc[r], a0);
    atomicAdd(&sacc[(r + 1) % 10], a1);
    atomicAdd(&sacc[(r + 2) % 10], a2);
    atomicAdd(&sacc[(r + 3) % 10], a3);
    __syncthreads();
    if (threadIdx.x < 10) atomicAdd(&s[b * 16 + threadIdx.x], sacc[threadIdx.x]);
}

// ---------------------------------------------------------------------------
// K6: tiny MLP + log_softmax(axis=0). One block; ~µs.
// ---------------------------------------------------------------------------
__global__ void mlp_kernel(const float* __restrict__ s,
                           const float* __restrict__ x,
                           const float* __restrict__ W_gcn,
                           const float* __restrict__ b_gcn,
                           const float* __restrict__ W1, const float* __restrict__ b1,
                           const float* __restrict__ W2, const float* __restrict__ b2,
                           const float* __restrict__ Wo, const float* __restrict__ bo,
                           float* __restrict__ out) {
    __shared__ float h0[32][20];
    __shared__ float h1[32][80];
    __shared__ float h2[32][160];
    __shared__ float o[32][4];
    const int tid = threadIdx.x;

    for (int idx = tid; idx < 32 * 20; idx += blockDim.x) {
        const int b = idx / 20, j = idx % 20;
        float v;
        if (j < 10) {
            v = 0.0f;
#pragma unroll
            for (int k = 0; k < 10; ++k) v += s[b * 16 + k] * W_gcn[k * 10 + j];
            v = v * (1.0f / (float)N_NODES) + b_gcn[j];
        } else {
            v = x[b * 10 + (j - 10)];
        }
        h0[b][j] = v;
    }
    __syncthreads();

    for (int idx = tid; idx < 32 * 80; idx += blockDim.x) {
        const int b = idx / 80, j = idx % 80;
        float v = b1[j];
#pragma unroll
        for (int k = 0; k < 20; ++k) v += h0[b][k] * W1[k * 80 + j];
        h1[b][j] = (v > 0.0f) ? v : 0.01f * v;
    }
    __syncthreads();

    for (int idx = tid; idx < 32 * 160; idx += blockDim.x) {
        const int b = idx / 160, j = idx % 160;
        float v = b2[j];
        for (int k = 0; k < 80; ++k) v += h1[b][k] * W2[k * 160 + j];
        h2[b][j] = (v > 0.0f) ? v : 0.01f * v;
    }
    __syncthreads();

    for (int idx = tid; idx < 32 * 4; idx += blockDim.x) {
        const int b = idx / 4, j = idx % 4;
        float v = bo[j];
        for (int k = 0; k < 160; ++k) v += h2[b][k] * Wo[k * 4 + j];
        o[b][j] = v;
    }
    __syncthreads();

    if (tid < 4) {
        float m = -1e30f;
        for (int b = 0; b < 32; ++b) m = fmaxf(m, o[b][tid]);
        float lse = 0.0f;
        for (int b = 0; b < 32; ++b) lse += expf(o[b][tid] - m);
        lse = logf(lse);
        for (int b = 0; b < 32; ++b) out[b * 4 + tid] = o[b][tid] - m - lse;
    }
}

extern "C" void kernel_launch(void* const* d_in, const int* in_sizes, int n_in,
                              void* d_out, int out_size, void* d_ws, size_t ws_size,
                              hipStream_t stream) {
    const float* x      = (const float*)d_in[0];
    const float* gcn_x  = (const float*)d_in[1];
    const int*   ei     = (const int*)d_in[2];
    const float* W_gcn  = (const float*)d_in[3];
    const float* b_gcn  = (const float*)d_in[4];
    const float* W1     = (const float*)d_in[5];
    const float* b1     = (const float*)d_in[6];
    const float* W2     = (const float*)d_in[7];
    const float* b2     = (const float*)d_in[8];
    const float* Wo     = (const float*)d_in[9];
    const float* bo     = (const float*)d_in[10];
    float* out = (float*)d_out;

    // workspace layout (offsets in bytes):
    //   s        [32*16 f32]            @ 0          (2 KB, zeroed)
    //   partials [256*25000 u32]        @ 2048       (25.6 MB; K1 uses 12.8 MB of it, K3 all)
    //   dinv     [32*50000 f32]         @ 25,602,048 (6.4 MB)
    //   qdinv    [32*25000 u32 packed]  @ 32,002,048 (3.2 MB)
    //   w        [32*50000 f32]         @ 35,202,048 (6.4 MB)   total ~41.6 MB
    float*    s        = (float*)d_ws;
    unsigned* partials = (unsigned*)((char*)d_ws + 2048);
    float*    dinv     = (float*)((char*)d_ws + 2048 + (size_t)256 * NWORDC * 4);
    unsigned* qdinv    = (unsigned*)((char*)dinv + (size_t)BATCH * N_NODES * 4);
    float*    w        = (float*)((char*)qdinv + (size_t)BATCH * (N_NODES / 2) * 4);

    // allow 100 KB dynamic LDS for the full-range c histogram (idempotent)
    hipFuncSetAttribute((const void*)cscat_kernel,
                        hipFuncAttributeMaxDynamicSharedMemorySize, NWORDC * 4);

    hipMemsetAsync(s, 0, BATCH * 16 * sizeof(float), stream);

    {   // K1: degree histograms
        dim3 grid(CHUNKS, BATCH);
        hist_kernel<<<grid, 1024, 0, stream>>>(ei, partials);
    }
    {   // K2: reduce -> dinv, qdinv
        const int n = BATCH * NWORD8;
        dinv_kernel<<<(n + 255) / 256, 256, 0, stream>>>(partials, dinv, qdinv);
    }
    {   // K3: full-range c-scatter histograms (256 swizzled blocks, 100 KB LDS)
        cscat_kernel<<<256, 1024, NWORDC * 4, stream>>>(ei, (const unsigned short*)qdinv,
                                                        partials);
    }
    {   // K4: w = dinv*(c+dinv)
        const int n = BATCH * NWORDC;
        w_kernel<<<(n + 255) / 256, 256, 0, stream>>>(partials, dinv, w);
    }
    {   // K5: pooled weighted column-sum (float4)
        dim3 grid(CHUNKS, BATCH);
        pool_kernel<<<grid, 320, 0, stream>>>(gcn_x, w, s);
    }
    mlp_kernel<<<1, 256, 0, stream>>>(s, x, W_gcn, b_gcn, W1, b1, W2, b2, Wo, bo, out);
}

// Round 4
// 435.245 us; speedup vs baseline: 4.8553x; 1.1860x over previous
//
#include <hip/hip_runtime.h>

#define N_NODES 50000
#define N_EDGES 800000
#define BATCH   32
#define NWORD8  12500   // N_NODES/4 u32 words (u8-packed deg counts / qd8 table)
#define NWORDC  25000   // N_NODES/2 u32 words, u16-packed c (full range, 100 KB)
#define CHUNKS  8       // cscat chunks
#define EPC4    25000   // cscat int4 loads per chunk (= 100000 edges)
#define HCHUNKS 16      // hist chunks (512 blocks -> 2/CU)
#define HEPC4   12500   // hist int4 loads per chunk (= 50000 edges)
#define QSCALE  255.0f

// ---------------------------------------------------------------------------
// K1: per-(batch,chunk) degree histogram in LDS (u8 packed x4 per u32 word).
// 16 chunks -> 512 blocks -> 2 blocks/CU (32 waves). Per-chunk per-node count
// ~ Poisson(1): u8 overflow impossible in practice. No global atomics.
// ---------------------------------------------------------------------------
__global__ __launch_bounds__(1024) void hist_kernel(const int* __restrict__ ei,
                                                    unsigned* __restrict__ partials) {
    const int chunk = blockIdx.x, b = blockIdx.y;
    __shared__ unsigned cnt[NWORD8];  // 50 KB
    for (int i = threadIdx.x; i < NWORD8; i += 1024) cnt[i] = 0;
    __syncthreads();
    const int4* __restrict__ dst4 =
        (const int4*)(ei + (size_t)b * (2 * N_EDGES) + N_EDGES) + (size_t)chunk * HEPC4;
    for (int i = threadIdx.x; i < HEPC4; i += 1024) {
        const int4 v = dst4[i];
        atomicAdd(&cnt[((unsigned)v.x) >> 2], 1u << ((v.x & 3) * 8));
        atomicAdd(&cnt[((unsigned)v.y) >> 2], 1u << ((v.y & 3) * 8));
        atomicAdd(&cnt[((unsigned)v.z) >> 2], 1u << ((v.z & 3) * 8));
        atomicAdd(&cnt[((unsigned)v.w) >> 2], 1u << ((v.w & 3) * 8));
    }
    __syncthreads();
    unsigned* __restrict__ out = partials + (size_t)(b * HCHUNKS + chunk) * NWORD8;
    for (int i = threadIdx.x; i < NWORD8; i += 1024) out[i] = cnt[i];
}

// ---------------------------------------------------------------------------
// K2: reduce degree partials -> dinv[b][n] = rsqrt(count+1) (f32)
//     and qd8 = round(dinv * 255) packed x4 per u32 (LDS gather table for K3).
// ---------------------------------------------------------------------------
__global__ void dinv_kernel(const unsigned* __restrict__ partials,
                            float* __restrict__ dinv,
                            unsigned* __restrict__ qd8) {
    const int idx = blockIdx.x * 256 + threadIdx.x;
    if (idx >= BATCH * NWORD8) return;
    const int b = idx / NWORD8, i = idx - b * NWORD8;
    const unsigned* __restrict__ p = partials + (size_t)(b * HCHUNKS) * NWORD8 + i;
    unsigned d0 = 0, d1 = 0, d2 = 0, d3 = 0;
#pragma unroll
    for (int c = 0; c < HCHUNKS; ++c) {
        const unsigned v = p[(size_t)c * NWORD8];
        d0 += v & 0xFF; d1 += (v >> 8) & 0xFF; d2 += (v >> 16) & 0xFF; d3 += v >> 24;
    }
    const float i0 = rsqrtf((float)(d0 + 1));
    const float i1 = rsqrtf((float)(d1 + 1));
    const float i2 = rsqrtf((float)(d2 + 1));
    const float i3 = rsqrtf((float)(d3 + 1));
    float4* dv4 = (float4*)(dinv + (size_t)b * N_NODES) + i;
    *dv4 = make_float4(i0, i1, i2, i3);
    const unsigned q0 = __float2uint_rn(i0 * QSCALE);
    const unsigned q1 = __float2uint_rn(i1 * QSCALE);
    const unsigned q2 = __float2uint_rn(i2 * QSCALE);
    const unsigned q3 = __float2uint_rn(i3 * QSCALE);
    qd8[(size_t)b * NWORD8 + i] = q0 | (q1 << 8) | (q2 << 16) | (q3 << 24);
}

// ---------------------------------------------------------------------------
// K3: c[n] = sum over out-edges of n of dinv[dst], u16 fixed-point histogram
// over the FULL node range. The dst-side dinv table lives in LDS as u8
// (50 KB) so the random gather is a ds_read_u8, NOT a divergent global load
// (R3 post-mortem: 25.6M divergent global gathers were the 147 µs bottleneck).
// Dynamic LDS = 100 KB histogram + 50 KB qd8 = 150 KB; 256 blocks = 1/CU.
// u16 overflow needs >=257 same-src hits in a 100k-edge chunk: P ~ 0.
// ---------------------------------------------------------------------------
__global__ __launch_bounds__(1024) void cscat_kernel(const int* __restrict__ ei,
                                                     const unsigned* __restrict__ qd8,
                                                     unsigned* __restrict__ cpart) {
    extern __shared__ unsigned smem[];           // [0,25000): cs, [25000,37500): qd8
    unsigned* cs = smem;
    const unsigned char* qs = (const unsigned char*)(smem + NWORDC);
    const int id = blockIdx.x;  // 256 = 8 xcd * 4 bgroup * 8 chunk
    const int b = (id & 7) + 8 * ((id >> 3) & 3);
    const int chunk = id >> 5;
    for (int i = threadIdx.x; i < NWORDC; i += 1024) cs[i] = 0;
    {   // stage the batch's u8 dinv table into LDS (coalesced, 50 KB)
        const unsigned* __restrict__ src = qd8 + (size_t)b * NWORD8;
        unsigned* dst = smem + NWORDC;
        for (int i = threadIdx.x; i < NWORD8; i += 1024) dst[i] = src[i];
    }
    __syncthreads();
    const int* eb = ei + (size_t)b * (2 * N_EDGES);
    const int4* __restrict__ src4 = (const int4*)eb + (size_t)chunk * EPC4;
    const int4* __restrict__ dst4 = (const int4*)(eb + N_EDGES) + (size_t)chunk * EPC4;
    for (int i = threadIdx.x; i < EPC4; i += 1024) {
        const int4 s4 = src4[i];
        const int4 d4 = dst4[i];
        const unsigned q0 = qs[d4.x];
        const unsigned q1 = qs[d4.y];
        const unsigned q2 = qs[d4.z];
        const unsigned q3 = qs[d4.w];
        atomicAdd(&cs[((unsigned)s4.x) >> 1], q0 << ((s4.x & 1) << 4));
        atomicAdd(&cs[((unsigned)s4.y) >> 1], q1 << ((s4.y & 1) << 4));
        atomicAdd(&cs[((unsigned)s4.z) >> 1], q2 << ((s4.z & 1) << 4));
        atomicAdd(&cs[((unsigned)s4.w) >> 1], q3 << ((s4.w & 1) << 4));
    }
    __syncthreads();
    unsigned* __restrict__ out = cpart + (size_t)(b * CHUNKS + chunk) * NWORDC;
    for (int i = threadIdx.x; i < NWORDC; i += 1024) out[i] = cs[i];
}

// ---------------------------------------------------------------------------
// K4: w[b][n] = dinv * (c + dinv)   (the +dinv folds the self-loop dinv^2)
// ---------------------------------------------------------------------------
__global__ void w_kernel(const unsigned* __restrict__ cpart,
                         const float* __restrict__ dinv,
                         float* __restrict__ w) {
    const int idx = blockIdx.x * 256 + threadIdx.x;
    if (idx >= BATCH * NWORDC) return;
    const int b = idx / NWORDC, i = idx - b * NWORDC;
    const unsigned* __restrict__ p = cpart + (size_t)(b * CHUNKS) * NWORDC + i;
    unsigned c0 = 0, c1 = 0;
#pragma unroll
    for (int c = 0; c < CHUNKS; ++c) {
        const unsigned v = p[(size_t)c * NWORDC];
        c0 += v & 0xFFFF; c1 += v >> 16;
    }
    const int node = 2 * i;
    const float2 d = *((const float2*)(dinv + (size_t)b * N_NODES + node));
    const float f0 = (float)c0 * (1.0f / QSCALE);
    const float f1 = (float)c1 * (1.0f / QSCALE);
    *((float2*)(w + (size_t)b * N_NODES + node)) = make_float2(d.x * (f0 + d.x), d.y * (f1 + d.y));
}

// ---------------------------------------------------------------------------
// K5: s[b][:] = sum_n xg[b,n,:] * w[b,n] — float4 coalesced weighted col-sum.
// 320 threads: 4*320 % 10 == 0 so each lane's 4 channels are loop-invariant.
// ---------------------------------------------------------------------------
__global__ __launch_bounds__(320) void pool_kernel(const float* __restrict__ xg,
                                                   const float* __restrict__ w,
                                                   float* __restrict__ s) {
    const int chunk = blockIdx.x, b = blockIdx.y;  // grid (8, 32)
    const float4* __restrict__ xg4 = (const float4*)xg;
    const int base4 = b * 125000 + chunk * 15625;  // float4 index; 4*base4 % 10 == 0
    const int r = (4 * threadIdx.x) % 10;          // element phase, fixed per lane
    float a0 = 0.0f, a1 = 0.0f, a2 = 0.0f, a3 = 0.0f;
    for (int j = threadIdx.x; j < 15625; j += 320) {
        const int f4 = base4 + j;
        const int e0 = f4 * 4;             // global element idx; w idx = e0/10
        const float4 v = xg4[f4];
        const float w0 = w[e0 / 10];
        const float w1 = (r == 8) ? w[e0 / 10 + 1] : w0;  // r==8: z,w cross node boundary
        a0 += v.x * w0;
        a1 += v.y * w0;
        a2 += v.z * w1;
        a3 += v.w * w1;
    }
    __shared__ float sacc[10];
    if (threadIdx.x < 10) sacc[threadIdx.x] = 0.0f;
    __syncthreads();
    atomicAdd(&sacc[r], a0);
    atomicAdd(&sacc[(r + 1) % 10], a1);
    atomicAdd(&sacc[(r + 2) % 10], a2);
    atomicAdd(&sacc[(r + 3) % 10], a3);
    __syncthreads();
    if (threadIdx.x < 10) atomicAdd(&s[b * 16 + threadIdx.x], sacc[threadIdx.x]);
}

// ---------------------------------------------------------------------------
// K6: tiny MLP + log_softmax(axis=0). One block; ~µs.
// ---------------------------------------------------------------------------
__global__ void mlp_kernel(const float* __restrict__ s,
                           const float* __restrict__ x,
                           const float* __restrict__ W_gcn,
                           const float* __restrict__ b_gcn,
                           const float* __restrict__ W1, const float* __restrict__ b1,
                           const float* __restrict__ W2, const float* __restrict__ b2,
                           const float* __restrict__ Wo, const float* __restrict__ bo,
                           float* __restrict__ out) {
    __shared__ float h0[32][20];
    __shared__ float h1[32][80];
    __shared__ float h2[32][160];
    __shared__ float o[32][4];
    const int tid = threadIdx.x;

    for (int idx = tid; idx < 32 * 20; idx += blockDim.x) {
        const int b = idx / 20, j = idx % 20;
        float v;
        if (j < 10) {
            v = 0.0f;
#pragma unroll
            for (int k = 0; k < 10; ++k) v += s[b * 16 + k] * W_gcn[k * 10 + j];
            v = v * (1.0f / (float)N_NODES) + b_gcn[j];
        } else {
            v = x[b * 10 + (j - 10)];
        }
        h0[b][j] = v;
    }
    __syncthreads();

    for (int idx = tid; idx < 32 * 80; idx += blockDim.x) {
        const int b = idx / 80, j = idx % 80;
        float v = b1[j];
#pragma unroll
        for (int k = 0; k < 20; ++k) v += h0[b][k] * W1[k * 80 + j];
        h1[b][j] = (v > 0.0f) ? v : 0.01f * v;
    }
    __syncthreads();

    for (int idx = tid; idx < 32 * 160; idx += blockDim.x) {
        const int b = idx / 160, j = idx % 160;
        float v = b2[j];
        for (int k = 0; k < 80; ++k) v += h1[b][k] * W2[k * 160 + j];
        h2[b][j] = (v > 0.0f) ? v : 0.01f * v;
    }
    __syncthreads();

    for (int idx = tid; idx < 32 * 4; idx += blockDim.x) {
        const int b = idx / 4, j = idx % 4;
        float v = bo[j];
        for (int k = 0; k < 160; ++k) v += h2[b][k] * Wo[k * 4 + j];
        o[b][j] = v;
    }
    __syncthreads();

    if (tid < 4) {
        float m = -1e30f;
        for (int b = 0; b < 32; ++b) m = fmaxf(m, o[b][tid]);
        float lse = 0.0f;
        for (int b = 0; b < 32; ++b) lse += expf(o[b][tid] - m);
        lse = logf(lse);
        for (int b = 0; b < 32; ++b) out[b * 4 + tid] = o[b][tid] - m - lse;
    }
}

extern "C" void kernel_launch(void* const* d_in, const int* in_sizes, int n_in,
                              void* d_out, int out_size, void* d_ws, size_t ws_size,
                              hipStream_t stream) {
    const float* x      = (const float*)d_in[0];
    const float* gcn_x  = (const float*)d_in[1];
    const int*   ei     = (const int*)d_in[2];
    const float* W_gcn  = (const float*)d_in[3];
    const float* b_gcn  = (const float*)d_in[4];
    const float* W1     = (const float*)d_in[5];
    const float* b1     = (const float*)d_in[6];
    const float* W2     = (const float*)d_in[7];
    const float* b2     = (const float*)d_in[8];
    const float* Wo     = (const float*)d_in[9];
    const float* bo     = (const float*)d_in[10];
    float* out = (float*)d_out;

    // workspace layout (offsets in bytes):
    //   s        [32*16 f32]            @ 0          (2 KB, zeroed)
    //   partials [512*12500 u32]        @ 2048       (25.6 MB; K1 16-chunk / K3 8-chunk reuse)
    //   dinv     [32*50000 f32]         @ 25,602,048 (6.4 MB)
    //   qd8      [32*12500 u32 packed]  @ 32,002,048 (1.6 MB)
    //   w        [32*50000 f32]         @ 33,602,048 (6.4 MB)   total ~40 MB
    float*    s        = (float*)d_ws;
    unsigned* partials = (unsigned*)((char*)d_ws + 2048);
    float*    dinv     = (float*)((char*)d_ws + 2048 + (size_t)512 * NWORD8 * 4);
    unsigned* qd8      = (unsigned*)((char*)dinv + (size_t)BATCH * N_NODES * 4);
    float*    w        = (float*)((char*)qd8 + (size_t)BATCH * NWORD8 * 4);

    // 150 KB dynamic LDS for c-histogram (100 KB) + u8 dinv table (50 KB)
    hipFuncSetAttribute((const void*)cscat_kernel,
                        hipFuncAttributeMaxDynamicSharedMemorySize,
                        (NWORDC + NWORD8) * 4);

    hipMemsetAsync(s, 0, BATCH * 16 * sizeof(float), stream);

    {   // K1: degree histograms (512 blocks -> 2/CU)
        dim3 grid(HCHUNKS, BATCH);
        hist_kernel<<<grid, 1024, 0, stream>>>(ei, partials);
    }
    {   // K2: reduce -> dinv (f32), qd8 (u8 packed)
        const int n = BATCH * NWORD8;
        dinv_kernel<<<(n + 255) / 256, 256, 0, stream>>>(partials, dinv, qd8);
    }
    {   // K3: full-range c-scatter, LDS-resident gather table (150 KB LDS)
        cscat_kernel<<<256, 1024, (NWORDC + NWORD8) * 4, stream>>>(ei, qd8, partials);
    }
    {   // K4: w = dinv*(c+dinv)
        const int n = BATCH * NWORDC;
        w_kernel<<<(n + 255) / 256, 256, 0, stream>>>(partials, dinv, w);
    }
    {   // K5: pooled weighted column-sum (float4)
        dim3 grid(CHUNKS, BATCH);
        pool_kernel<<<grid, 320, 0, stream>>>(gcn_x, w, s);
    }
    mlp_kernel<<<1, 256, 0, stream>>>(s, x, W_gcn, b_gcn, W1, b1, W2, b2, Wo, bo, out);
}

// Round 5
// 408.820 us; speedup vs baseline: 5.1692x; 1.0646x over previous
//
#include <hip/hip_runtime.h>

#define N_NODES 50000
#define N_EDGES 800000
#define BATCH   32
#define NWORD8  12500   // N_NODES/4 u32 words (u8-packed deg counts / qd8 table)
#define NWORDC  25000   // N_NODES/2 u32 words, u16-packed c (full range, 100 KB)
#define CHUNKS  8       // cscat chunks
#define EPC4    25000   // cscat int4 loads per chunk (= 100000 edges)
#define HCHUNKS 16      // hist chunks (512 blocks -> 2/CU)
#define HEPC4   12500   // hist int4 loads per chunk (= 50000 edges)
#define QSCALE  255.0f
#define PTHREADS 640    // pool threads: 640*4 % 10 == 0 keeps per-lane phase const

// ---------------------------------------------------------------------------
// K1: per-(batch,chunk) degree histogram in LDS (u8 packed x4 per u32 word).
// 16 chunks -> 512 blocks -> 2 blocks/CU (32 waves). No global atomics.
// ---------------------------------------------------------------------------
__global__ __launch_bounds__(1024) void hist_kernel(const int* __restrict__ ei,
                                                    unsigned* __restrict__ partials) {
    const int chunk = blockIdx.x, b = blockIdx.y;
    __shared__ unsigned cnt[NWORD8];  // 50 KB
    for (int i = threadIdx.x; i < NWORD8; i += 1024) cnt[i] = 0;
    __syncthreads();
    const int4* __restrict__ dst4 =
        (const int4*)(ei + (size_t)b * (2 * N_EDGES) + N_EDGES) + (size_t)chunk * HEPC4;
    for (int i = threadIdx.x; i < HEPC4; i += 1024) {
        const int4 v = dst4[i];
        atomicAdd(&cnt[((unsigned)v.x) >> 2], 1u << ((v.x & 3) * 8));
        atomicAdd(&cnt[((unsigned)v.y) >> 2], 1u << ((v.y & 3) * 8));
        atomicAdd(&cnt[((unsigned)v.z) >> 2], 1u << ((v.z & 3) * 8));
        atomicAdd(&cnt[((unsigned)v.w) >> 2], 1u << ((v.w & 3) * 8));
    }
    __syncthreads();
    unsigned* __restrict__ out = partials + (size_t)(b * HCHUNKS + chunk) * NWORD8;
    for (int i = threadIdx.x; i < NWORD8; i += 1024) out[i] = cnt[i];
}

// ---------------------------------------------------------------------------
// K2: reduce degree partials -> dinv[b][n] = rsqrt(count+1) (f32)
//     and qd8 = round(dinv * 255) packed x4 per u32 (LDS gather table for K3).
// ---------------------------------------------------------------------------
__global__ void dinv_kernel(const unsigned* __restrict__ partials,
                            float* __restrict__ dinv,
                            unsigned* __restrict__ qd8) {
    const int idx = blockIdx.x * 256 + threadIdx.x;
    if (idx >= BATCH * NWORD8) return;
    const int b = idx / NWORD8, i = idx - b * NWORD8;
    const unsigned* __restrict__ p = partials + (size_t)(b * HCHUNKS) * NWORD8 + i;
    unsigned d0 = 0, d1 = 0, d2 = 0, d3 = 0;
#pragma unroll
    for (int c = 0; c < HCHUNKS; ++c) {
        const unsigned v = p[(size_t)c * NWORD8];
        d0 += v & 0xFF; d1 += (v >> 8) & 0xFF; d2 += (v >> 16) & 0xFF; d3 += v >> 24;
    }
    const float i0 = rsqrtf((float)(d0 + 1));
    const float i1 = rsqrtf((float)(d1 + 1));
    const float i2 = rsqrtf((float)(d2 + 1));
    const float i3 = rsqrtf((float)(d3 + 1));
    float4* dv4 = (float4*)(dinv + (size_t)b * N_NODES) + i;
    *dv4 = make_float4(i0, i1, i2, i3);
    const unsigned q0 = __float2uint_rn(i0 * QSCALE);
    const unsigned q1 = __float2uint_rn(i1 * QSCALE);
    const unsigned q2 = __float2uint_rn(i2 * QSCALE);
    const unsigned q3 = __float2uint_rn(i3 * QSCALE);
    qd8[(size_t)b * NWORD8 + i] = q0 | (q1 << 8) | (q2 << 16) | (q3 << 24);
}

// ---------------------------------------------------------------------------
// K3: c[n] = sum over out-edges of n of dinv[dst], u16 fixed-point histogram
// over the FULL node range. dst-side dinv table lives in LDS as u8 (50 KB):
// the random gather is a ds_read_u8, not a divergent global load.
// Dynamic LDS = 100 KB histogram + 50 KB qd8 = 150 KB; 256 blocks = 1/CU.
// ---------------------------------------------------------------------------
__global__ __launch_bounds__(1024) void cscat_kernel(const int* __restrict__ ei,
                                                     const unsigned* __restrict__ qd8,
                                                     unsigned* __restrict__ cpart) {
    extern __shared__ unsigned smem[];           // [0,25000): cs, [25000,37500): qd8
    unsigned* cs = smem;
    const unsigned char* qs = (const unsigned char*)(smem + NWORDC);
    const int id = blockIdx.x;  // 256 = 8 xcd * 4 bgroup * 8 chunk
    const int b = (id & 7) + 8 * ((id >> 3) & 3);
    const int chunk = id >> 5;
    for (int i = threadIdx.x; i < NWORDC; i += 1024) cs[i] = 0;
    {   // stage the batch's u8 dinv table into LDS (coalesced, 50 KB)
        const unsigned* __restrict__ src = qd8 + (size_t)b * NWORD8;
        unsigned* dst = smem + NWORDC;
        for (int i = threadIdx.x; i < NWORD8; i += 1024) dst[i] = src[i];
    }
    __syncthreads();
    const int* eb = ei + (size_t)b * (2 * N_EDGES);
    const int4* __restrict__ src4 = (const int4*)eb + (size_t)chunk * EPC4;
    const int4* __restrict__ dst4 = (const int4*)(eb + N_EDGES) + (size_t)chunk * EPC4;
    for (int i = threadIdx.x; i < EPC4; i += 1024) {
        const int4 s4 = src4[i];
        const int4 d4 = dst4[i];
        const unsigned q0 = qs[d4.x];
        const unsigned q1 = qs[d4.y];
        const unsigned q2 = qs[d4.z];
        const unsigned q3 = qs[d4.w];
        atomicAdd(&cs[((unsigned)s4.x) >> 1], q0 << ((s4.x & 1) << 4));
        atomicAdd(&cs[((unsigned)s4.y) >> 1], q1 << ((s4.y & 1) << 4));
        atomicAdd(&cs[((unsigned)s4.z) >> 1], q2 << ((s4.z & 1) << 4));
        atomicAdd(&cs[((unsigned)s4.w) >> 1], q3 << ((s4.w & 1) << 4));
    }
    __syncthreads();
    unsigned* __restrict__ out = cpart + (size_t)(b * CHUNKS + chunk) * NWORDC;
    for (int i = threadIdx.x; i < NWORDC; i += 1024) out[i] = cs[i];
}

// ---------------------------------------------------------------------------
// K4: w[b][n] = dinv * (c + dinv)   (the +dinv folds the self-loop dinv^2)
// ---------------------------------------------------------------------------
__global__ void w_kernel(const unsigned* __restrict__ cpart,
                         const float* __restrict__ dinv,
                         float* __restrict__ w) {
    const int idx = blockIdx.x * 256 + threadIdx.x;
    if (idx >= BATCH * NWORDC) return;
    const int b = idx / NWORDC, i = idx - b * NWORDC;
    const unsigned* __restrict__ p = cpart + (size_t)(b * CHUNKS) * NWORDC + i;
    unsigned c0 = 0, c1 = 0;
#pragma unroll
    for (int c = 0; c < CHUNKS; ++c) {
        const unsigned v = p[(size_t)c * NWORDC];
        c0 += v & 0xFFFF; c1 += v >> 16;
    }
    const int node = 2 * i;
    const float2 d = *((const float2*)(dinv + (size_t)b * N_NODES + node));
    const float f0 = (float)c0 * (1.0f / QSCALE);
    const float f1 = (float)c1 * (1.0f / QSCALE);
    *((float2*)(w + (size_t)b * N_NODES + node)) = make_float2(d.x * (f0 + d.x), d.y * (f1 + d.y));
}

// ---------------------------------------------------------------------------
// K5: pooled weighted column-sum, float4 coalesced. 640 threads (10 waves/CU,
// 2x the R4 latency-hiding). 640*4 % 10 == 0 -> per-lane channel phase is
// loop-invariant. Per-wave LDS accumulator rows (low contention), then
// per-block partials written WITHOUT global atomics (removes memset dispatch).
// ---------------------------------------------------------------------------
__global__ __launch_bounds__(PTHREADS) void pool_kernel(const float* __restrict__ xg,
                                                        const float* __restrict__ w,
                                                        float* __restrict__ spart) {
    const int chunk = blockIdx.x, b = blockIdx.y;  // grid (8, 32)
    const float4* __restrict__ xg4 = (const float4*)xg;
    const int base4 = b * 125000 + chunk * 15625;  // float4 index; 4*base4 % 10 == 0
    const int r = (4 * threadIdx.x) % 10;          // element phase, fixed per lane
    float a0 = 0.0f, a1 = 0.0f, a2 = 0.0f, a3 = 0.0f;
    for (int j = threadIdx.x; j < 15625; j += PTHREADS) {
        const int f4 = base4 + j;
        const int e0 = f4 * 4;             // global element idx; w idx = e0/10
        const float4 v = xg4[f4];
        const float w0 = w[e0 / 10];
        const float w1 = (r == 8) ? w[e0 / 10 + 1] : w0;  // r==8: z,w cross node boundary
        a0 += v.x * w0;
        a1 += v.y * w0;
        a2 += v.z * w1;
        a3 += v.w * w1;
    }
    __shared__ float sacc[PTHREADS / 64][10];
    const int wave = threadIdx.x >> 6;
    if ((threadIdx.x & 63) < 10) sacc[wave][threadIdx.x & 63] = 0.0f;
    __syncthreads();
    atomicAdd(&sacc[wave][r], a0);
    atomicAdd(&sacc[wave][(r + 1) % 10], a1);
    atomicAdd(&sacc[wave][(r + 2) % 10], a2);
    atomicAdd(&sacc[wave][(r + 3) % 10], a3);
    __syncthreads();
    if (threadIdx.x < 10) {
        float v = 0.0f;
#pragma unroll
        for (int wv = 0; wv < PTHREADS / 64; ++wv) v += sacc[wv][threadIdx.x];
        spart[(b * CHUNKS + chunk) * 16 + threadIdx.x] = v;
    }
}

// ---------------------------------------------------------------------------
// K6: reduce pool partials + tiny MLP + log_softmax(axis=0). One block.
// ---------------------------------------------------------------------------
__global__ __launch_bounds__(512) void mlp_kernel(const float* __restrict__ spart,
                           const float* __restrict__ x,
                           const float* __restrict__ W_gcn,
                           const float* __restrict__ b_gcn,
                           const float* __restrict__ W1, const float* __restrict__ b1,
                           const float* __restrict__ W2, const float* __restrict__ b2,
                           const float* __restrict__ Wo, const float* __restrict__ bo,
                           float* __restrict__ out) {
    __shared__ float ssum[32][10];
    __shared__ float h0[32][20];
    __shared__ float h1[32][80];
    __shared__ float h2[32][160];
    __shared__ float o[32][4];
    const int tid = threadIdx.x;

    for (int idx = tid; idx < 32 * 10; idx += blockDim.x) {
        const int b = idx / 10, k = idx % 10;
        float v = 0.0f;
#pragma unroll
        for (int c = 0; c < CHUNKS; ++c) v += spart[(b * CHUNKS + c) * 16 + k];
        ssum[b][k] = v;
    }
    __syncthreads();

    for (int idx = tid; idx < 32 * 20; idx += blockDim.x) {
        const int b = idx / 20, j = idx % 20;
        float v;
        if (j < 10) {
            v = 0.0f;
#pragma unroll
            for (int k = 0; k < 10; ++k) v += ssum[b][k] * W_gcn[k * 10 + j];
            v = v * (1.0f / (float)N_NODES) + b_gcn[j];
        } else {
            v = x[b * 10 + (j - 10)];
        }
        h0[b][j] = v;
    }
    __syncthreads();

    for (int idx = tid; idx < 32 * 80; idx += blockDim.x) {
        const int b = idx / 80, j = idx % 80;
        float v = b1[j];
#pragma unroll
        for (int k = 0; k < 20; ++k) v += h0[b][k] * W1[k * 80 + j];
        h1[b][j] = (v > 0.0f) ? v : 0.01f * v;
    }
    __syncthreads();

    for (int idx = tid; idx < 32 * 160; idx += blockDim.x) {
        const int b = idx / 160, j = idx % 160;
        float v = b2[j];
        for (int k = 0; k < 80; ++k) v += h1[b][k] * W2[k * 160 + j];
        h2[b][j] = (v > 0.0f) ? v : 0.01f * v;
    }
    __syncthreads();

    for (int idx = tid; idx < 32 * 4; idx += blockDim.x) {
        const int b = idx / 4, j = idx % 4;
        float v = bo[j];
        for (int k = 0; k < 160; ++k) v += h2[b][k] * Wo[k * 4 + j];
        o[b][j] = v;
    }
    __syncthreads();

    if (tid < 4) {
        float m = -1e30f;
        for (int b = 0; b < 32; ++b) m = fmaxf(m, o[b][tid]);
        float lse = 0.0f;
        for (int b = 0; b < 32; ++b) lse += expf(o[b][tid] - m);
        lse = logf(lse);
        for (int b = 0; b < 32; ++b) out[b * 4 + tid] = o[b][tid] - m - lse;
    }
}

extern "C" void kernel_launch(void* const* d_in, const int* in_sizes, int n_in,
                              void* d_out, int out_size, void* d_ws, size_t ws_size,
                              hipStream_t stream) {
    const float* x      = (const float*)d_in[0];
    const float* gcn_x  = (const float*)d_in[1];
    const int*   ei     = (const int*)d_in[2];
    const float* W_gcn  = (const float*)d_in[3];
    const float* b_gcn  = (const float*)d_in[4];
    const float* W1     = (const float*)d_in[5];
    const float* b1     = (const float*)d_in[6];
    const float* W2     = (const float*)d_in[7];
    const float* b2     = (const float*)d_in[8];
    const float* Wo     = (const float*)d_in[9];
    const float* bo     = (const float*)d_in[10];
    float* out = (float*)d_out;

    // workspace layout (offsets in bytes):
    //   partials [512*12500 u32]        @ 0          (25.6 MB; hist 16-chunk / cscat 8-chunk reuse)
    //   dinv     [32*50000 f32]         @ 25,600,000 (6.4 MB)
    //   qd8      [32*12500 u32 packed]  @ 32,000,000 (1.6 MB)
    //   w        [32*50000 f32]         @ 33,600,000 (6.4 MB)
    //   spart    [32*8*16 f32]          @ 40,000,000 (16 KB)    total ~40 MB
    unsigned* partials = (unsigned*)d_ws;
    float*    dinv     = (float*)((char*)d_ws + (size_t)512 * NWORD8 * 4);
    unsigned* qd8      = (unsigned*)((char*)dinv + (size_t)BATCH * N_NODES * 4);
    float*    w        = (float*)((char*)qd8 + (size_t)BATCH * NWORD8 * 4);
    float*    spart    = (float*)((char*)w + (size_t)BATCH * N_NODES * 4);

    // 150 KB dynamic LDS for c-histogram (100 KB) + u8 dinv table (50 KB)
    hipFuncSetAttribute((const void*)cscat_kernel,
                        hipFuncAttributeMaxDynamicSharedMemorySize,
                        (NWORDC + NWORD8) * 4);

    {   // K1: degree histograms (512 blocks -> 2/CU)
        dim3 grid(HCHUNKS, BATCH);
        hist_kernel<<<grid, 1024, 0, stream>>>(ei, partials);
    }
    {   // K2: reduce -> dinv (f32), qd8 (u8 packed)
        const int n = BATCH * NWORD8;
        dinv_kernel<<<(n + 255) / 256, 256, 0, stream>>>(partials, dinv, qd8);
    }
    {   // K3: full-range c-scatter, LDS-resident gather table (150 KB LDS)
        cscat_kernel<<<256, 1024, (NWORDC + NWORD8) * 4, stream>>>(ei, qd8, partials);
    }
    {   // K4: w = dinv*(c+dinv)
        const int n = BATCH * NWORDC;
        w_kernel<<<(n + 255) / 256, 256, 0, stream>>>(partials, dinv, w);
    }
    {   // K5: pooled weighted column-sum (float4, 10 waves/CU, no atomics)
        dim3 grid(CHUNKS, BATCH);
        pool_kernel<<<grid, PTHREADS, 0, stream>>>(gcn_x, w, spart);
    }
    mlp_kernel<<<1, 512, 0, stream>>>(spart, x, W_gcn, b_gcn, W1, b1, W2, b2, Wo, bo, out);
}